// Round 1
// baseline (1152.032 us; speedup 1.0000x reference)
//
#include <hip/hip_runtime.h>
#include <cstddef>

// Problem constants (fixed by the reference).
#define B_ 256
#define S_ 10000
#define T_ 2000   // (10000 - 5)/5 + 1

// ---------- fast math helpers ----------
__device__ __forceinline__ float sigf(float x) {
  // sigmoid via v_exp + v_rcp; saturates correctly at +/-inf
  return __builtin_amdgcn_rcpf(1.f + __expf(-x));
}
__device__ __forceinline__ float tanhf_(float x) {
  // tanh(x) = 1 - 2/(1+e^{2x}); saturates correctly
  return 1.f - 2.f * __builtin_amdgcn_rcpf(1.f + __expf(2.f * x));
}
__device__ __forceinline__ float rdlane(float v, int lane) {
  return __int_as_float(__builtin_amdgcn_readlane(__float_as_int(v), lane));
}

// DPP move (old=0). ctrl/row_mask must be ICE -> macro.
#define DPP_MOV(v, ctrl, rm, bc) \
  __int_as_float(__builtin_amdgcn_update_dpp(0, __float_as_int(v), (ctrl), (rm), 0xf, (bc)))

// Sum of all 64 lanes (distinct values), result broadcast via readlane(63).
__device__ __forceinline__ float wsum64(float v) {
  v += DPP_MOV(v, 0x111, 0xf, true);   // row_shr:1
  v += DPP_MOV(v, 0x112, 0xf, true);   // row_shr:2
  v += DPP_MOV(v, 0x114, 0xf, true);   // row_shr:4
  v += DPP_MOV(v, 0x118, 0xf, true);   // row_shr:8  -> lane15 of each row16 = row sum
  v += DPP_MOV(v, 0x142, 0xa, false);  // row_bcast15 into rows 1,3
  v += DPP_MOV(v, 0x143, 0xc, false);  // row_bcast31 into rows 2,3 -> lane63 = total
  return rdlane(v, 63);
}
// Sum of 16 distinct values where lane j holds value (j>>2) (quad-duplicated).
// shr4+shr8 collapse each row16 to its 4 distinct values; bcasts combine rows.
__device__ __forceinline__ float wsum16q(float v) {
  v += DPP_MOV(v, 0x114, 0xf, true);
  v += DPP_MOV(v, 0x118, 0xf, true);
  v += DPP_MOV(v, 0x142, 0xa, false);
  v += DPP_MOV(v, 0x143, 0xc, false);
  return rdlane(v, 63);   // exact sum over the 16 distinct values
}

// ---------- K1: MLP(1->16)+ReLU -> Conv1d(16->16,k5,s5) -> sigmoid -> seq[B,T,16] ----------
__global__ __launch_bounds__(256) void k_conv(
    const float* __restrict__ x, const float* __restrict__ Wm,
    const float* __restrict__ bm, const float* __restrict__ Wc,
    const float* __restrict__ bconv, float* __restrict__ seq) {
  const int idx = blockIdx.x * 256 + threadIdx.x;  // = b*T + t ; grid is exact
  const int b = idx / T_;
  const int t = idx - b * T_;
  const float* xp = x + (size_t)b * S_ + (size_t)t * 5;
  const float x0 = xp[0], x1 = xp[1], x2 = xp[2], x3 = xp[3], x4 = xp[4];
  float acc[16];
#pragma unroll
  for (int o = 0; o < 16; ++o) acc[o] = bconv[o];
#pragma unroll
  for (int i = 0; i < 16; ++i) {
    const float wmi = Wm[i], bmi = bm[i];   // uniform -> scalar loads
    const float u0 = fmaxf(fmaf(x0, wmi, bmi), 0.f);
    const float u1 = fmaxf(fmaf(x1, wmi, bmi), 0.f);
    const float u2 = fmaxf(fmaf(x2, wmi, bmi), 0.f);
    const float u3 = fmaxf(fmaf(x3, wmi, bmi), 0.f);
    const float u4 = fmaxf(fmaf(x4, wmi, bmi), 0.f);
#pragma unroll
    for (int o = 0; o < 16; ++o) {
      const float* w = Wc + o * 80 + i * 5;  // W_conv[o][i][k], uniform -> s_load
      float a = acc[o];
      a = fmaf(u0, w[0], a);
      a = fmaf(u1, w[1], a);
      a = fmaf(u2, w[2], a);
      a = fmaf(u3, w[3], a);
      a = fmaf(u4, w[4], a);
      acc[o] = a;
    }
  }
  float4* sp = reinterpret_cast<float4*>(seq + (size_t)idx * 16);
#pragma unroll
  for (int qq = 0; qq < 4; ++qq) {
    float4 r;
    r.x = sigf(acc[qq * 4 + 0]);
    r.y = sigf(acc[qq * 4 + 1]);
    r.z = sigf(acc[qq * 4 + 2]);
    r.w = sigf(acc[qq * 4 + 3]);
    sp[qq] = r;
  }
}

// ---------- K2: x-path gates precompute: xln[bt*64 + j] = LN_j(seq[bt]@Wx^T)*gx+bx+bG ----------
// One wave per (b,t); lane j owns gate gj = (j&3)*16 + (j>>2)  (quad-interleaved,
// matching the LSTM kernel so the store/load is identity-indexed).
__global__ __launch_bounds__(256) void k_xgate(
    const float* __restrict__ seq, const float* __restrict__ Wx,
    const float* __restrict__ gx, const float* __restrict__ bx,
    const float* __restrict__ bG, float* __restrict__ xln) {
  const int gtid = blockIdx.x * 256 + threadIdx.x;
  const int wid = gtid >> 6;  // (b*T + t)
  const int j = gtid & 63;
  const int gj = ((j & 3) << 4) | (j >> 2);
  const float* sv = seq + (size_t)wid * 16;   // wave-uniform -> scalar loads
  const float* wrow = Wx + gj * 16;
  float za = 0.f, zb = 0.f;
#pragma unroll
  for (int m = 0; m < 8; ++m) za = fmaf(sv[m], wrow[m], za);
#pragma unroll
  for (int m = 8; m < 16; ++m) zb = fmaf(sv[m], wrow[m], zb);
  const float z = za + zb;
  const float s = wsum64(z);
  const float s2 = wsum64(z * z);
  const float mean = s * (1.f / 64.f);
  const float var = fmaf(s2, 1.f / 64.f, -mean * mean);
  const float rs = __builtin_amdgcn_rsqf(var + 1e-5f);
  xln[(size_t)wid * 64 + j] = fmaf((z - mean) * rs, gx[gj], bx[gj] + bG[gj]);
}

// ---------- K3: sequential LSTM scan, one wave (64 lanes) per batch element ----------
// Lane j owns gate gj=(j&3)*16+(j>>2): quadrant q=j&3 in {i,f,g,o}, hidden index k=j>>2.
// All cross-lane traffic is DPP / v_readlane -- no LDS, no barriers.
template <bool XLN>
__global__ __launch_bounds__(64) void k_lstm(
    const float* __restrict__ seq, const float* __restrict__ xln,
    const float* __restrict__ Wx, const float* __restrict__ Wh,
    const float* __restrict__ bG, const float* __restrict__ gx,
    const float* __restrict__ bx, const float* __restrict__ gh,
    const float* __restrict__ bh, const float* __restrict__ gc,
    const float* __restrict__ bc, const float* __restrict__ Wcls,
    const float* __restrict__ bcls, const float* __restrict__ h0,
    const float* __restrict__ c0, float* __restrict__ out) {
  const int b = blockIdx.x;
  const int j = threadIdx.x;
  const int q = j & 3;
  const int k = j >> 2;
  const int gj = (q << 4) | k;

  float wh[16];
#pragma unroll
  for (int m = 0; m < 16; ++m) wh[m] = Wh[gj * 16 + m];

  float wx[16];
  float gxj = 0.f, bxj = 0.f;
  if (!XLN) {
#pragma unroll
    for (int m = 0; m < 16; ++m) wx[m] = Wx[gj * 16 + m];
    gxj = gx[gj];
    bxj = bx[gj] + bG[gj];   // fold b_gates into the x-path bias
  }
  const float ghj = gh[gj];
  const float bhj = bh[gj];
  const float gck = gc[k];
  const float bck = bc[k];
  const bool isg = (q == 2);                  // g-gate -> tanh = 2*sigmoid(2x)-1
  const float ascale = isg ? 2.f : 1.f;
  const float amul = isg ? 2.f : 1.f;
  const float asub = isg ? 1.f : 0.f;

  float c = c0[b * 16 + k];
  float hs[16];                                // uniform (SGPR) copy of h
#pragma unroll
  for (int m = 0; m < 16; ++m) hs[m] = h0[b * 16 + m];

  const size_t base = (size_t)b * T_;
  float xg_cur = 0.f;
  float xv_cur[16];
  if (XLN) {
    xg_cur = xln[base * 64 + j];
  } else {
    const float* sv = seq + base * 16;
#pragma unroll
    for (int m = 0; m < 16; ++m) xv_cur[m] = sv[m];
  }

  for (int t = 0; t < T_; ++t) {
    // prefetch next step's x-path data (off the critical chain)
    const int tn = (t + 1 < T_) ? (t + 1) : t;
    float xg_nxt = 0.f;
    float xv_nxt[16];
    if (XLN) {
      xg_nxt = xln[(base + tn) * 64 + j];
    } else {
      const float* sv = seq + (base + tn) * 16;
#pragma unroll
      for (int m = 0; m < 16; ++m) xv_nxt[m] = sv[m];
    }

    // x-path contribution: LN(xt@Wx^T)*gx + bx + b_gates
    float xn;
    if (XLN) {
      xn = xg_cur;
    } else {
      float za = 0.f, zb = 0.f;
#pragma unroll
      for (int m = 0; m < 8; ++m) za = fmaf(wx[m], xv_cur[m], za);
#pragma unroll
      for (int m = 8; m < 16; ++m) zb = fmaf(wx[m], xv_cur[m], zb);
      const float z = za + zb;
      const float s = wsum64(z);
      const float s2 = wsum64(z * z);
      const float mean = s * (1.f / 64.f);
      const float var = fmaf(s2, 1.f / 64.f, -mean * mean);
      const float rs = __builtin_amdgcn_rsqf(var + 1e-5f);
      xn = fmaf((z - mean) * rs, gxj, bxj);
    }

    // h-path: matvec with h in SGPRs, then LN over the 64 lanes
    float ha = 0.f, hb2 = 0.f;
#pragma unroll
    for (int m = 0; m < 8; ++m) ha = fmaf(wh[m], hs[m], ha);
#pragma unroll
    for (int m = 8; m < 16; ++m) hb2 = fmaf(wh[m], hs[m], hb2);
    const float hz = ha + hb2;
    const float s = wsum64(hz);
    const float s2 = wsum64(hz * hz);
    const float mean = s * (1.f / 64.f);
    const float var = fmaf(s2, 1.f / 64.f, -mean * mean);
    const float rs = __builtin_amdgcn_rsqf(var + 1e-5f);
    const float hn = fmaf((hz - mean) * rs, ghj, bhj);

    const float gate = xn + hn;
    const float act = fmaf(amul, sigf(ascale * gate), -asub);

    // gather i,f,g,o for this lane's k from its quad (DPP quad_perm)
    const float iv = DPP_MOV(act, 0x00, 0xf, true);
    const float fv = DPP_MOV(act, 0x55, 0xf, true);
    const float gv = DPP_MOV(act, 0xAA, 0xf, true);
    const float ov = DPP_MOV(act, 0xFF, 0xf, true);

    c = fmaf(fv, c, iv * gv);

    // LN over the 16 c values (quad-duplicated layout -> wsum16q is exact)
    const float cs = wsum16q(c);
    const float cs2 = wsum16q(c * c);
    const float cm = cs * (1.f / 16.f);
    const float cvv = fmaf(cs2, 1.f / 16.f, -cm * cm);
    const float crs = __builtin_amdgcn_rsqf(cvv + 1e-5f);
    const float cn = fmaf((c - cm) * crs, gck, bck);
    const float hv = ov * tanhf_(cn);   // lane j holds h[k], k=j>>2 (x4 copies)

    // broadcast h back to SGPRs for the next step's matvec
#pragma unroll
    for (int m = 0; m < 16; ++m) hs[m] = rdlane(hv, 4 * m);

    xg_cur = xg_nxt;
    if (!XLN) {
#pragma unroll
      for (int m = 0; m < 16; ++m) xv_cur[m] = xv_nxt[m];
    }
  }

  // classifier: sigmoid(h @ W_cls^T + b_cls)
  float dot = bcls[0];
#pragma unroll
  for (int m = 0; m < 16; ++m) dot = fmaf(hs[m], Wcls[m], dot);
  if (j == 0) out[b] = sigf(dot);
}

// ---------- host ----------
extern "C" void kernel_launch(void* const* d_in, const int* in_sizes, int n_in,
                              void* d_out, int out_size, void* d_ws, size_t ws_size,
                              hipStream_t stream) {
  (void)in_sizes; (void)n_in; (void)out_size;
  const float* x    = (const float*)d_in[0];
  const float* Wm   = (const float*)d_in[1];
  const float* bm   = (const float*)d_in[2];
  const float* Wc   = (const float*)d_in[3];
  const float* bcv  = (const float*)d_in[4];
  const float* Wx   = (const float*)d_in[5];
  const float* Wh   = (const float*)d_in[6];
  const float* bG   = (const float*)d_in[7];
  const float* gx   = (const float*)d_in[8];
  const float* bx   = (const float*)d_in[9];
  const float* gh   = (const float*)d_in[10];
  const float* bh   = (const float*)d_in[11];
  const float* gc   = (const float*)d_in[12];
  const float* bc   = (const float*)d_in[13];
  const float* Wcls = (const float*)d_in[14];
  const float* bcls = (const float*)d_in[15];
  const float* h0   = (const float*)d_in[16];
  const float* c0   = (const float*)d_in[17];
  float* out = (float*)d_out;

  const size_t seq_bytes = (size_t)B_ * T_ * 16 * sizeof(float);  // 32.768 MB
  const size_t xln_bytes = (size_t)B_ * T_ * 64 * sizeof(float);  // 131.072 MB
  float* seq = (float*)d_ws;
  float* xln = (float*)((char*)d_ws + seq_bytes);
  const bool use_xln = ws_size >= seq_bytes + xln_bytes;  // deterministic across calls

  k_conv<<<dim3((B_ * T_) / 256), dim3(256), 0, stream>>>(x, Wm, bm, Wc, bcv, seq);
  if (use_xln) {
    k_xgate<<<dim3((B_ * T_ * 64) / 256), dim3(256), 0, stream>>>(seq, Wx, gx, bx, bG, xln);
    k_lstm<true><<<dim3(B_), dim3(64), 0, stream>>>(
        seq, xln, Wx, Wh, bG, gx, bx, gh, bh, gc, bc, Wcls, bcls, h0, c0, out);
  } else {
    k_lstm<false><<<dim3(B_), dim3(64), 0, stream>>>(
        seq, xln, Wx, Wh, bG, gx, bx, gh, bh, gc, bc, Wcls, bcls, h0, c0, out);
  }
}

// Round 2
// 799.336 us; speedup vs baseline: 1.4412x; 1.4412x over previous
//
#include <hip/hip_runtime.h>
#include <cstddef>

// Problem constants (fixed by the reference).
#define B_ 256
#define S_ 10000
#define T_ 2000   // (10000 - 5)/5 + 1
#define TB_ 500   // T_/4

// ---------- fast math helpers ----------
__device__ __forceinline__ float sigf(float x) {
  return __builtin_amdgcn_rcpf(1.f + __expf(-x));
}
__device__ __forceinline__ float rdlane(float v, int lane) {
  return __int_as_float(__builtin_amdgcn_readlane(__float_as_int(v), lane));
}

// DPP move (old=0). ctrl/row_mask must be ICE -> macro.
#define DPP_MOV(v, ctrl, rm, bc) \
  __int_as_float(__builtin_amdgcn_update_dpp(0, __float_as_int(v), (ctrl), (rm), 0xf, (bc)))

// Sum of all 64 lanes (distinct values), result broadcast via readlane(63).
// Verified on HW in round 1 (absmax 0.0).
__device__ __forceinline__ float wsum64(float v) {
  v += DPP_MOV(v, 0x111, 0xf, true);   // row_shr:1
  v += DPP_MOV(v, 0x112, 0xf, true);   // row_shr:2
  v += DPP_MOV(v, 0x114, 0xf, true);   // row_shr:4
  v += DPP_MOV(v, 0x118, 0xf, true);   // row_shr:8
  v += DPP_MOV(v, 0x142, 0xa, false);  // row_bcast15 -> rows 1,3
  v += DPP_MOV(v, 0x143, 0xc, false);  // row_bcast31 -> rows 2,3 ; lane63 = total
  return rdlane(v, 63);
}
// Sum of 16 distinct values where lane j holds value (j>>2) (quad-duplicated).
__device__ __forceinline__ float wsum16q(float v) {
  v += DPP_MOV(v, 0x114, 0xf, true);
  v += DPP_MOV(v, 0x118, 0xf, true);
  v += DPP_MOV(v, 0x142, 0xa, false);
  v += DPP_MOV(v, 0x143, 0xc, false);
  return rdlane(v, 63);
}

// ---------- K1: MLP(1->16)+ReLU -> Conv1d(16->16,k5,s5) -> sigmoid -> seq[B,T,16] ----------
__global__ __launch_bounds__(256) void k_conv(
    const float* __restrict__ x, const float* __restrict__ Wm,
    const float* __restrict__ bm, const float* __restrict__ Wc,
    const float* __restrict__ bconv, float* __restrict__ seq) {
  const int idx = blockIdx.x * 256 + threadIdx.x;  // = b*T + t ; grid is exact
  const int b = idx / T_;
  const int t = idx - b * T_;
  const float* xp = x + (size_t)b * S_ + (size_t)t * 5;
  const float x0 = xp[0], x1 = xp[1], x2 = xp[2], x3 = xp[3], x4 = xp[4];
  float acc[16];
#pragma unroll
  for (int o = 0; o < 16; ++o) acc[o] = bconv[o];
#pragma unroll
  for (int i = 0; i < 16; ++i) {
    const float wmi = Wm[i], bmi = bm[i];
    const float u0 = fmaxf(fmaf(x0, wmi, bmi), 0.f);
    const float u1 = fmaxf(fmaf(x1, wmi, bmi), 0.f);
    const float u2 = fmaxf(fmaf(x2, wmi, bmi), 0.f);
    const float u3 = fmaxf(fmaf(x3, wmi, bmi), 0.f);
    const float u4 = fmaxf(fmaf(x4, wmi, bmi), 0.f);
#pragma unroll
    for (int o = 0; o < 16; ++o) {
      const float* w = Wc + o * 80 + i * 5;  // W_conv[o][i][k], uniform -> s_load
      float a = acc[o];
      a = fmaf(u0, w[0], a);
      a = fmaf(u1, w[1], a);
      a = fmaf(u2, w[2], a);
      a = fmaf(u3, w[3], a);
      a = fmaf(u4, w[4], a);
      acc[o] = a;
    }
  }
  float4* sp = reinterpret_cast<float4*>(seq + (size_t)idx * 16);
#pragma unroll
  for (int qq = 0; qq < 4; ++qq) {
    float4 r;
    r.x = sigf(acc[qq * 4 + 0]);
    r.y = sigf(acc[qq * 4 + 1]);
    r.z = sigf(acc[qq * 4 + 2]);
    r.w = sigf(acc[qq * 4 + 3]);
    sp[qq] = r;
  }
}

// ---------- K2: packed x-gate precompute ----------
// One wave per (b, tb) handles 4 consecutive time steps t = 4*tb + u.
// Lane j owns gate gj = (j&3)*16 + (j>>2). Stores, per lane, a float4 of
//   sx = sgn * (LN(xt@Wx^T)*gx + bx + b_gates),  sgn = -2 for g-gates else -1
// (negation folds the sigmoid's -x; the 2x folds tanh(g)=2*sig(2g)-1).
__global__ __launch_bounds__(256) void k_xgate(
    const float* __restrict__ seq, const float* __restrict__ Wx,
    const float* __restrict__ gx, const float* __restrict__ bx,
    const float* __restrict__ bG, float4* __restrict__ xln4) {
  const int gtid = blockIdx.x * 256 + threadIdx.x;
  const int wid = gtid >> 6;  // b*TB_ + tb
  const int j = gtid & 63;
  const int q = j & 3;
  const int gj = ((j & 3) << 4) | (j >> 2);
  float wrow[16];
#pragma unroll
  for (int m = 0; m < 16; ++m) wrow[m] = Wx[gj * 16 + m];
  const float sgn = (q == 2) ? -2.f : -1.f;
  const float gxa = gx[gj] * sgn;
  const float bxa = (bx[gj] + bG[gj]) * sgn;
  const float* sv = seq + (size_t)wid * 64;  // 4 rows of 16, wave-uniform
  float outv[4];
#pragma unroll
  for (int u = 0; u < 4; ++u) {
    const float* s0 = sv + u * 16;
    float za = 0.f, zb = 0.f;
#pragma unroll
    for (int m = 0; m < 8; ++m) za = fmaf(s0[m], wrow[m], za);
#pragma unroll
    for (int m = 8; m < 16; ++m) zb = fmaf(s0[m], wrow[m], zb);
    const float z = za + zb;
    const float s = wsum64(z);
    const float s2 = wsum64(z * z);
    const float mean = s * (1.f / 64.f);
    const float var = fmaf(s2, 1.f / 64.f, -mean * mean);
    const float rs = __builtin_amdgcn_rsqf(var + 1e-5f);
    outv[u] = fmaf((z - mean) * rs, gxa, bxa);
  }
  float4 r;
  r.x = outv[0]; r.y = outv[1]; r.z = outv[2]; r.w = outv[3];
  xln4[(size_t)wid * 64 + j] = r;
}

// ---------- one LSTM step (chain-optimized) ----------
// sx = pre-negated/pre-doubled x-gate value for this lane's gate.
// Returns hv (lane j holds h[j>>2], quad-replicated); caller rebroadcasts.
__device__ __forceinline__ float lstm_step(
    float sx, float& c, const float hs[16], const float wh[16],
    float ghp, float bhn, float amul, float abias, float gck2, float bck2) {
  // z = Wh[gj,:] . h  -- 4 parallel chains of 4, then 2-level tree
  float p0 = wh[0] * hs[0];
  float p1 = wh[4] * hs[4];
  float p2 = wh[8] * hs[8];
  float p3 = wh[12] * hs[12];
#pragma unroll
  for (int m = 1; m < 4; ++m) {
    p0 = fmaf(wh[m], hs[m], p0);
    p1 = fmaf(wh[4 + m], hs[4 + m], p1);
    p2 = fmaf(wh[8 + m], hs[8 + m], p2);
    p3 = fmaf(wh[12 + m], hs[12 + m], p3);
  }
  const float z = (p0 + p1) + (p2 + p3);
  // LN stats over the 64 gate pre-activations (two parallel DPP chains)
  const float s = wsum64(z);
  const float s2 = wsum64(z * z);
  const float mean = s * (1.f / 64.f);
  const float var = fmaf(s2, (1.f / 64.f), -mean * mean);
  const float rs = __builtin_amdgcn_rsqf(var + 1e-5f);
  // ngate = -(scale)*(xn + LN(z)*gh + bh) ; sx already holds -(scale)*xn part
  const float P = rs * ghp;                 // ghp = (q==2?2:1)*gh
  const float tB = sx + bhn;                // bhn = -(q==2?2:1)*bh (ready early)
  const float Bv = fmaf(mean, P, tB);
  const float ngate = fmaf(-z, P, Bv);
  const float r = __builtin_amdgcn_rcpf(1.f + __expf(ngate));  // = sigma(scale*gate)
  const float act = fmaf(amul, r, abias);   // i,f,o: r ; g: 2r-1 = tanh(g)
  // gather i,f,g,o within the quad
  const float iv = DPP_MOV(act, 0x00, 0xf, true);
  const float fv = DPP_MOV(act, 0x55, 0xf, true);
  const float gv = DPP_MOV(act, 0xAA, 0xf, true);
  const float ov = DPP_MOV(act, 0xFF, 0xf, true);
  c = fmaf(fv, c, iv * gv);
  const float ov2 = -2.f * ov;              // off the critical path
  // LN over the 16 c values (quad-duplicated)
  const float cs = wsum16q(c);
  const float cs2 = wsum16q(c * c);
  const float cm = cs * (1.f / 16.f);
  const float cvv = fmaf(cs2, (1.f / 16.f), -cm * cm);
  const float crs = __builtin_amdgcn_rsqf(cvv + 1e-5f);
  const float Ac = crs * gck2;              // gck2 = 2*gc -> cn2 = 2*LN(c)aff
  const float Bc = fmaf(-cm, Ac, bck2);     // bck2 = 2*bc
  const float cn2 = fmaf(c, Ac, Bc);
  const float r2 = __builtin_amdgcn_rcpf(1.f + __expf(cn2));
  return fmaf(ov2, r2, ov);                 // h = o * tanh(LN(c)) = o*(1-2*r2)
}

// ---------- K3: sequential LSTM scan, one wave per batch element ----------
template <bool XLN>
__global__ __launch_bounds__(64) void k_lstm(
    const float* __restrict__ seq, const float4* __restrict__ xln4,
    const float* __restrict__ Wx, const float* __restrict__ Wh,
    const float* __restrict__ bG, const float* __restrict__ gx,
    const float* __restrict__ bx, const float* __restrict__ gh,
    const float* __restrict__ bh, const float* __restrict__ gc,
    const float* __restrict__ bc, const float* __restrict__ Wcls,
    const float* __restrict__ bcls, const float* __restrict__ h0,
    const float* __restrict__ c0, float* __restrict__ out) {
  const int b = blockIdx.x;
  const int j = threadIdx.x;
  const int q = j & 3;
  const int k = j >> 2;
  const int gj = (q << 4) | k;

  float wh[16];
#pragma unroll
  for (int m = 0; m < 16; ++m) wh[m] = Wh[gj * 16 + m];

  const float sc = (q == 2) ? 2.f : 1.f;
  const float ghp = gh[gj] * sc;
  const float bhn = -bh[gj] * sc;
  const float amul = (q == 2) ? 2.f : 1.f;
  const float abias = (q == 2) ? -1.f : 0.f;
  const float gck2 = 2.f * gc[k];
  const float bck2 = 2.f * bc[k];

  float c = c0[b * 16 + k];
  float hs[16];  // wave-uniform (SGPRs after readlane)
#pragma unroll
  for (int m = 0; m < 16; ++m) hs[m] = h0[b * 16 + m];

  if (XLN) {
    const float4* xp = xln4 + (size_t)b * TB_ * 64 + j;
    float4 xc = xp[0];
    float4 xn = xp[64];
#pragma unroll 2
    for (int tb = 0; tb < TB_; ++tb) {
      const int tpf = (tb + 2 < TB_) ? (tb + 2) : (TB_ - 1);
      const float4 xf = xp[(size_t)tpf * 64];  // 8-step-ahead prefetch
      {
        const float hv = lstm_step(xc.x, c, hs, wh, ghp, bhn, amul, abias, gck2, bck2);
#pragma unroll
        for (int m = 0; m < 16; ++m) hs[m] = rdlane(hv, 4 * m);
      }
      {
        const float hv = lstm_step(xc.y, c, hs, wh, ghp, bhn, amul, abias, gck2, bck2);
#pragma unroll
        for (int m = 0; m < 16; ++m) hs[m] = rdlane(hv, 4 * m);
      }
      {
        const float hv = lstm_step(xc.z, c, hs, wh, ghp, bhn, amul, abias, gck2, bck2);
#pragma unroll
        for (int m = 0; m < 16; ++m) hs[m] = rdlane(hv, 4 * m);
      }
      {
        const float hv = lstm_step(xc.w, c, hs, wh, ghp, bhn, amul, abias, gck2, bck2);
#pragma unroll
        for (int m = 0; m < 16; ++m) hs[m] = rdlane(hv, 4 * m);
      }
      xc = xn;
      xn = xf;
    }
  } else {
    // fallback: compute x-path inline from seq (no workspace layout needed)
    float wx[16];
#pragma unroll
    for (int m = 0; m < 16; ++m) wx[m] = Wx[gj * 16 + m];
    const float gxa = gx[gj] * -sc;
    const float bxa = (bx[gj] + bG[gj]) * -sc;
    const float* sv0 = seq + (size_t)b * T_ * 16;
    for (int t = 0; t < T_; ++t) {
      const float* sv = sv0 + (size_t)t * 16;
      float za = 0.f, zb = 0.f;
#pragma unroll
      for (int m = 0; m < 8; ++m) za = fmaf(sv[m], wx[m], za);
#pragma unroll
      for (int m = 8; m < 16; ++m) zb = fmaf(sv[m], wx[m], zb);
      const float z = za + zb;
      const float s = wsum64(z);
      const float s2 = wsum64(z * z);
      const float mean = s * (1.f / 64.f);
      const float var = fmaf(s2, 1.f / 64.f, -mean * mean);
      const float rs = __builtin_amdgcn_rsqf(var + 1e-5f);
      const float sx = fmaf((z - mean) * rs, gxa, bxa);
      const float hv = lstm_step(sx, c, hs, wh, ghp, bhn, amul, abias, gck2, bck2);
#pragma unroll
      for (int m = 0; m < 16; ++m) hs[m] = rdlane(hv, 4 * m);
    }
  }

  // classifier: sigmoid(h @ W_cls^T + b_cls)
  float dot = bcls[0];
#pragma unroll
  for (int m = 0; m < 16; ++m) dot = fmaf(hs[m], Wcls[m], dot);
  if (j == 0) out[b] = sigf(dot);
}

// ---------- host ----------
extern "C" void kernel_launch(void* const* d_in, const int* in_sizes, int n_in,
                              void* d_out, int out_size, void* d_ws, size_t ws_size,
                              hipStream_t stream) {
  (void)in_sizes; (void)n_in; (void)out_size;
  const float* x    = (const float*)d_in[0];
  const float* Wm   = (const float*)d_in[1];
  const float* bm   = (const float*)d_in[2];
  const float* Wc   = (const float*)d_in[3];
  const float* bcv  = (const float*)d_in[4];
  const float* Wx   = (const float*)d_in[5];
  const float* Wh   = (const float*)d_in[6];
  const float* bG   = (const float*)d_in[7];
  const float* gx   = (const float*)d_in[8];
  const float* bx   = (const float*)d_in[9];
  const float* gh   = (const float*)d_in[10];
  const float* bh   = (const float*)d_in[11];
  const float* gc   = (const float*)d_in[12];
  const float* bc   = (const float*)d_in[13];
  const float* Wcls = (const float*)d_in[14];
  const float* bcls = (const float*)d_in[15];
  const float* h0   = (const float*)d_in[16];
  const float* c0   = (const float*)d_in[17];
  float* out = (float*)d_out;

  const size_t seq_bytes = (size_t)B_ * T_ * 16 * sizeof(float);     // 32.768 MB
  const size_t xln_bytes = (size_t)B_ * TB_ * 64 * sizeof(float4);   // 131.072 MB
  float* seq = (float*)d_ws;
  float4* xln4 = (float4*)((char*)d_ws + seq_bytes);
  const bool use_xln = ws_size >= seq_bytes + xln_bytes;

  k_conv<<<dim3((B_ * T_) / 256), dim3(256), 0, stream>>>(x, Wm, bm, Wc, bcv, seq);
  if (use_xln) {
    k_xgate<<<dim3((B_ * TB_ * 64) / 256), dim3(256), 0, stream>>>(seq, Wx, gx, bx, bG, xln4);
    k_lstm<true><<<dim3(B_), dim3(64), 0, stream>>>(
        seq, xln4, Wx, Wh, bG, gx, bx, gh, bh, gc, bc, Wcls, bcls, h0, c0, out);
  } else {
    k_lstm<false><<<dim3(B_), dim3(64), 0, stream>>>(
        seq, xln4, Wx, Wh, bG, gx, bx, gh, bh, gc, bc, Wcls, bcls, h0, c0, out);
  }
}